// Round 12
// baseline (225.559 us; speedup 1.0000x reference)
//
#include <hip/hip_runtime.h>

typedef __attribute__((ext_vector_type(8))) short bf16x8;
typedef __attribute__((ext_vector_type(4))) float f32x4;

__device__ __forceinline__ float bf2f(unsigned short u) {
  return __uint_as_float(((unsigned int)u) << 16);
}
__device__ __forceinline__ unsigned short f2bf(float f) {
  unsigned int u = __float_as_uint(f);
  u += 0x7fffu + ((u >> 16) & 1u);
  return (unsigned short)(u >> 16);
}

// ---------------- workspace layout (bytes) ----------------
constexpr size_t OFF_XPAD = 0;
constexpr size_t SZ_XPAD  = (size_t)8 * 66 * 66 * 128 * 2;        // 8,921,088
constexpr size_t OFF_WB   = OFF_XPAD + SZ_XPAD;
constexpr size_t SZ_WB    = (size_t)9 * 16 * 256 * 8 * 2;         // 589,824
constexpr size_t OFF_WS2  = OFF_WB + SZ_WB;
constexpr size_t SZ_WS2   = (size_t)16 * 256 * 8 * 2;             // 65,536
constexpr size_t OFF_WO   = OFF_WS2 + SZ_WS2;
constexpr size_t SZ_WO    = (size_t)9 * 16 * 32 * 8 * 2;          // 73,728
// y and shortcut, bf16, FINAL NCHW layout: [8][256][64*64]
constexpr size_t OFF_YM   = OFF_WO + SZ_WO;
constexpr size_t SZ_YM    = (size_t)8 * 256 * 4096 * 2;           // 16,777,216
constexpr size_t OFF_SC   = OFF_YM + SZ_YM;
constexpr size_t SZ_SC    = SZ_YM;                                 // 16,777,216
constexpr size_t OFF_SR   = OFF_SC + SZ_SC;                        // statsRaw [8][256][2] f32
constexpr size_t SZ_SR    = (size_t)8 * 256 * 2 * 4;              // 16,384

// XCD swizzle: b = blk&7 -> batch b on XCD b (R2: FETCH 26->7.3MB). BN stats via
// per-batch atomics (R6). NT stores only with full-line-per-instruction coverage
// (R8) and only for streaming outputs, protecting the xpad gather set (R9/R10).
// R11 lessons: 2-tap gather pipeline = 2x regression (register blowup) - reverted;
// At stride 136->140 shorts = bank-conflict fix (2.47M->106K) - kept.
// R12: k_main emits y AND shortcut directly in NCHW bf16 (epilogue LDS transpose,
// proven ~free in R6); k_final becomes a pure elementwise stream.

// ---------------- prep: x transpose (0..511) + weight pack (512..689) + stats zero (690) ----------------
__global__ __launch_bounds__(256) void k_prep(const float* __restrict__ x,
                                              unsigned short* __restrict__ xp,
                                              const float* __restrict__ wdef,
                                              const float* __restrict__ wsc,
                                              const float* __restrict__ woff,
                                              unsigned short* __restrict__ wB,
                                              unsigned short* __restrict__ wS,
                                              unsigned short* __restrict__ wO,
                                              float* __restrict__ statsRaw) {
  int t = threadIdx.x;
  if (blockIdx.x == 690) {            // zero BN accumulators (graph-replay safe)
    for (int i = t; i < 4096; i += 256) statsRaw[i] = 0.f;
    return;
  }
  if (blockIdx.x >= 512) {            // ---- weight packing: 8 contiguous elems/thread ----
    int base = ((blockIdx.x - 512) * 256 + t) * 8;
    unsigned short w8[8];
    if (base < 294912) {
      int n = (base >> 3) & 255, kb = (base >> 11) & 15, tap = base >> 15;
#pragma unroll
      for (int j = 0; j < 8; ++j)
        w8[j] = f2bf(wdef[((size_t)n * 128 + kb * 8 + j) * 9 + tap]);
      *(bf16x8*)(wB + base) = *(const bf16x8*)w8;
    } else if (base < 327680) {
      int i0 = base - 294912;
      int n = (i0 >> 3) & 255, kb = i0 >> 11;
#pragma unroll
      for (int j = 0; j < 8; ++j)
        w8[j] = f2bf(wsc[(size_t)n * 128 + kb * 8 + j]);
      *(bf16x8*)(wS + i0) = *(const bf16x8*)w8;
    } else {
      int i0 = base - 327680;
      int n = (i0 >> 3) & 31, kb = (i0 >> 8) & 15, tap = i0 >> 12;
#pragma unroll
      for (int j = 0; j < 8; ++j)
        w8[j] = f2bf(n < 18 ? woff[((size_t)n * 128 + kb * 8 + j) * 9 + tap] : 0.f);
      *(bf16x8*)(wO + i0) = *(const bf16x8*)w8;
    }
    return;
  }
  // ---- x: NCHW fp32 -> NHWC bf16 zero-padded (+ halo zeroing) ----
  int blk = blockIdx.x;               // 512; b = blk&7 (XCD-local), h = blk>>3
  int b = blk & 7, h = blk >> 3;
  __shared__ unsigned short xt[128 * 68];   // [c][w], stride 68
  {
    unsigned short* base = xp + (size_t)b * 66 * 66 * 128;
    ushort4 z4 = {0, 0, 0, 0};
    if (t < 64) {                     // side columns of padded row h+1
      int col = (t >> 5) ? 65 : 0;
      int i = t & 31;
      *(ushort4*)(base + ((size_t)(h + 1) * 66 + col) * 128 + i * 4) = z4;
    }
    if (h == 0) {                     // top and bottom padded rows
      for (int i = t; i < 2112; i += 256) {
        *(ushort4*)(base + (size_t)i * 4) = z4;
        *(ushort4*)(base + (size_t)65 * 66 * 128 + (size_t)i * 4) = z4;
      }
    }
  }
  {
    // lane-coalesced load: consecutive lanes -> consecutive float4
#pragma unroll
    for (int i4 = 0; i4 < 8; ++i4) {
      int idx = t + i4 * 256;         // 0..2047 over 128 rows x 16 float4
      int row = idx >> 4, col = (idx & 15) * 4;
      float4 f = *(const float4*)&x[(((size_t)b * 128 + row) * 64 + h) * 64 + col];
      ushort4 u4;
      u4.x = f2bf(f.x); u4.y = f2bf(f.y); u4.z = f2bf(f.z); u4.w = f2bf(f.w);
      *(ushort4*)&xt[row * 68 + col] = u4;
    }
  }
  __syncthreads();
  {
    // column gather: lane = w (2-way bank alias only), cg = channel group
    int w = t & 63, cg = t >> 6;
    unsigned short tmp[32];
#pragma unroll
    for (int i = 0; i < 32; ++i) tmp[i] = xt[(cg * 32 + i) * 68 + w];
    unsigned short* dst = xp + ((size_t)(b * 66 + h + 1) * 66 + (w + 1)) * 128 + cg * 32;
#pragma unroll
    for (int i8 = 0; i8 < 4; ++i8)
      *(bf16x8*)(dst + i8 * 8) = *(const bf16x8*)&tmp[i8 * 8];
  }
}

// ---------------- main: offset conv + deform-sample + 3x3 GEMM + shortcut 1x1 + NCHW emit ----------------
// 512 blocks x 512 thr (8 waves). R10-verified tap loop (Breg preload, single-slot
// gathers) + stride-140 At (bank fix). Epilogue: BN atomics, shortcut MFMA (xpad row
// L2-hot), then y and sc transposed through LDS to NCHW bf16, NT full-line stores.
__global__ __launch_bounds__(512, 4) void k_main(const unsigned short* __restrict__ xp,
                                                 const unsigned short* __restrict__ wB,
                                                 const unsigned short* __restrict__ wO,
                                                 const unsigned short* __restrict__ wS,
                                                 const float* __restrict__ boff,
                                                 const float* __restrict__ bdef,
                                                 const float* __restrict__ bsc,
                                                 unsigned short* __restrict__ ynchw,
                                                 unsigned short* __restrict__ scnchw,
                                                 float* __restrict__ statsRaw) {
  int blk = blockIdx.x;               // 512; b = blk&7 (XCD-local), h = blk>>3
  int b = blk & 7, h = blk >> 3;
  int t = threadIdx.x;
  int lane = t & 63, wid = t >> 6;    // 8 waves
  int m = lane & 15, quad = lane >> 4;
  __shared__ __align__(16) unsigned short At[2][64 * 140];  // 2 x 17920 B (stride 140)
  __shared__ __align__(16) unsigned short ytr[256 * 72];    // 36864 B (NCHW transpose)
  __shared__ float offsL[9][64][2];                          // 4608 B

  // ---- phase 0: inline offset conv (waves 0-3 compute this row's 18 offsets -> LDS) ----
  if (wid < 4) {
    f32x4 a0 = {0.f, 0.f, 0.f, 0.f}, a1 = {0.f, 0.f, 0.f, 0.f};
    int px = wid * 16 + m;
    const unsigned short* xbase = xp + ((size_t)(b * 66 + h) * 66 + px) * 128 + quad * 8;
    for (int tap = 0; tap < 9; ++tap) {
      const unsigned short* arow = xbase + ((tap / 3) * 66 + (tap % 3)) * 128;
#pragma unroll
      for (int kk = 0; kk < 4; ++kk) {
        bf16x8 a = *(const bf16x8*)(arow + kk * 32);
        const unsigned short* bb = wO + (size_t)(tap * 16 + kk * 4 + quad) * 256;
        bf16x8 b0 = *(const bf16x8*)(bb + m * 8);
        bf16x8 b1 = *(const bf16x8*)(bb + (16 + m) * 8);
        a0 = __builtin_amdgcn_mfma_f32_16x16x32_bf16(a, b0, a0, 0, 0, 0);
        a1 = __builtin_amdgcn_mfma_f32_16x16x32_bf16(a, b1, a1, 0, 0, 0);
      }
    }
#pragma unroll
    for (int r = 0; r < 4; ++r) {
      int pxs = wid * 16 + quad * 4 + r;
      offsL[m >> 1][pxs][m & 1] = a0[r] + boff[m];   // n=m in [0,16): tap=n>>1, comp=n&1
      if (m < 2) offsL[8][pxs][m] = a1[r] + boff[16 + m];
    }
  }

  f32x4 acc[4][2];
#pragma unroll
  for (int i = 0; i < 4; ++i)
#pragma unroll
    for (int j = 0; j < 2; ++j) acc[i][j] = (f32x4){0.f, 0.f, 0.f, 0.f};

  // sampling role: thread = px_s*8 + sub; 8 consecutive lanes cover one 128B chunk
  int px_s = t >> 3, sub = t & 7;
  const unsigned short* xb_base = xp + (size_t)b * 66 * 66 * 128;
  int nb = wid * 32;                  // mfma role: 32-ch N slice per wave, M=64 shared

  bf16x8 Breg[4][2];                  // this tap's wB fragments, preloaded
  auto loadB = [&](int tap) {
#pragma unroll
    for (int kk = 0; kk < 4; ++kk)
#pragma unroll
      for (int ns = 0; ns < 2; ++ns)
        Breg[kk][ns] = *(const bf16x8*)(wB + ((size_t)(tap * 16 + kk * 4 + quad) * 256 + nb + ns * 16 + m) * 8);
  };

  auto sample_prep = [&](int tap, float* wgt, const unsigned short** p) {
    float2 ov = *(const float2*)&offsL[tap][px_s][0];
    int ky = tap / 3 - 1, kx = tap % 3 - 1;
    float py = (float)(h + ky) + ov.x;
    float pxf = (float)(px_s + kx) + ov.y;
    float y0f = floorf(py), x0f = floorf(pxf);
    float fy = py - y0f, fx = pxf - x0f;
    int iy0 = (int)y0f, ix0 = (int)x0f;
#pragma unroll
    for (int j = 0; j < 4; ++j) {
      int iy = iy0 + (j >> 1), ix = ix0 + (j & 1);
      float wy = (j >> 1) ? fy : 1.f - fy;
      float wx = (j & 1) ? fx : 1.f - fx;
      bool valid = (iy >= 0) && (iy < 64) && (ix >= 0) && (ix < 64);
      int iyc = min(max(iy, 0), 63), ixc = min(max(ix, 0), 63);
      wgt[j] = valid ? wy * wx : 0.f;
      p[j] = xb_base + ((size_t)(iyc + 1) * 66 + (ixc + 1)) * 128 + sub * 8;
    }
  };
  auto load_g1 = [&](const unsigned short** p, int g, bf16x8* v) {
#pragma unroll
    for (int j = 0; j < 4; ++j)
      v[j] = *(const bf16x8*)(p[j] + g * 64);
  };
  auto store_g1 = [&](unsigned short* dst, int g, const float* wgt, bf16x8* v) {
    bf16x8 o;
#pragma unroll
    for (int j = 0; j < 8; ++j) {
      float s = fmaf(wgt[0], bf2f((unsigned short)v[0][j]),
                fmaf(wgt[1], bf2f((unsigned short)v[1][j]),
                fmaf(wgt[2], bf2f((unsigned short)v[2][j]),
                     wgt[3] * bf2f((unsigned short)v[3][j]))));
      o[j] = (short)f2bf(s);
    }
    *(bf16x8*)(dst + g * 64) = o;
  };
  auto mfma_half = [&](const unsigned short* buf, int kk0) {
#pragma unroll
    for (int kk = kk0; kk < kk0 + 2; ++kk) {
      bf16x8 af[4];
#pragma unroll
      for (int ms = 0; ms < 4; ++ms)
        af[ms] = *(const bf16x8*)(buf + (ms * 16 + m) * 140 + kk * 32 + quad * 8);
#pragma unroll
      for (int ns = 0; ns < 2; ++ns)
#pragma unroll
        for (int ms = 0; ms < 4; ++ms)
          acc[ms][ns] = __builtin_amdgcn_mfma_f32_16x16x32_bf16(af[ms], Breg[kk][ns], acc[ms][ns], 0, 0, 0);
    }
  };

  // prologue: B-frags for tap 0, then sample tap 0 into buf 0
  loadB(0);
  __syncthreads();                    // offsL ready
  {
    float wgt[4]; const unsigned short* p[4]; bf16x8 v0[4], v1[4];
    sample_prep(0, wgt, p);
    unsigned short* dst = &At[0][px_s * 140 + sub * 8];
    load_g1(p, 0, v0); load_g1(p, 1, v1);
    store_g1(dst, 0, wgt, v0); store_g1(dst, 1, wgt, v1);
  }
#pragma unroll
  for (int tap = 0; tap < 9; ++tap) {
    __syncthreads();
    const unsigned short* cur = At[tap & 1];
    unsigned short* dst = &At[(tap + 1) & 1][px_s * 140 + sub * 8];
    if (tap < 8) {
      float wgt[4]; const unsigned short* p[4]; bf16x8 v0[4], v1[4];
      sample_prep(tap + 1, wgt, p);
      load_g1(p, 0, v0);
      load_g1(p, 1, v1);
      mfma_half(cur, 0);              // regs + ds_read only: no vmcnt dependence
      store_g1(dst, 0, wgt, v0);
      mfma_half(cur, 2);
      loadB(tap + 1);                 // prefetch next tap's B
      store_g1(dst, 1, wgt, v1);
    } else {
      mfma_half(cur, 0);
      mfma_half(cur, 2);
    }
  }

  // ---- epilogue 1: bias fold + BN atomics ----
#pragma unroll
  for (int ns = 0; ns < 2; ++ns) {
    int n = nb + ns * 16 + m;
    float bias = bdef[n];
    float s = 0.f, q = 0.f;
#pragma unroll
    for (int ms = 0; ms < 4; ++ms)
#pragma unroll
      for (int r = 0; r < 4; ++r) {
        float v = acc[ms][ns][r] + bias;
        acc[ms][ns][r] = v;
        s += v;
        q += v * v;
      }
    s += __shfl_xor(s, 16); s += __shfl_xor(s, 32);
    q += __shfl_xor(q, 16); q += __shfl_xor(q, 32);
    if (quad == 0) {                  // 64 blocks share each address (batch-local)
      atomicAdd(&statsRaw[((size_t)b * 256 + n) * 2 + 0], s);
      atomicAdd(&statsRaw[((size_t)b * 256 + n) * 2 + 1], q);
    }
  }

  // ---- epilogue 2: 1x1 shortcut MFMA (xpad center row is L2-hot) ----
  f32x4 accS[4][2];
#pragma unroll
  for (int i = 0; i < 4; ++i)
#pragma unroll
    for (int j = 0; j < 2; ++j) accS[i][j] = (f32x4){0.f, 0.f, 0.f, 0.f};
  {
    const unsigned short* xrow = xp + ((size_t)(b * 66 + h + 1) * 66 + 1) * 128;
#pragma unroll
    for (int kk = 0; kk < 4; ++kk) {
      bf16x8 af[4];
#pragma unroll
      for (int ms = 0; ms < 4; ++ms)
        af[ms] = *(const bf16x8*)(xrow + (ms * 16 + m) * 128 + kk * 32 + quad * 8);
#pragma unroll
      for (int ns = 0; ns < 2; ++ns) {
        bf16x8 bfr = *(const bf16x8*)(wS + ((size_t)(kk * 4 + quad) * 256 + nb + ns * 16 + m) * 8);
#pragma unroll
        for (int ms = 0; ms < 4; ++ms)
          accS[ms][ns] = __builtin_amdgcn_mfma_f32_16x16x32_bf16(af[ms], bfr, accS[ms][ns], 0, 0, 0);
      }
    }
  }

  // ---- epilogue 3: NCHW transpose-emit of y then sc (NT full-line stores) ----
  __syncthreads();                    // all waves done reading At (ytr is separate)
  {
#pragma unroll
    for (int ns = 0; ns < 2; ++ns) {
      int n = nb + ns * 16 + m;
#pragma unroll
      for (int ms = 0; ms < 4; ++ms) {
        unsigned short y4[4];
#pragma unroll
        for (int r = 0; r < 4; ++r) y4[r] = f2bf(acc[ms][ns][r]);
        *(ushort4*)&ytr[n * 72 + ms * 16 + quad * 4] = *(const ushort4*)y4;
      }
    }
  }
  __syncthreads();
  {
    int n = t >> 1, half = t & 1;     // pairs of lanes -> one 128B line
    const unsigned short* lrow = ytr + n * 72 + half * 32;
    unsigned short* grow = ynchw + ((size_t)(b * 256 + n) << 12) + h * 64 + half * 32;
#pragma unroll
    for (int i = 0; i < 4; ++i)
      __builtin_nontemporal_store(*(const bf16x8*)(lrow + i * 8), (bf16x8*)(grow + i * 8));
  }
  __syncthreads();
  {
#pragma unroll
    for (int ns = 0; ns < 2; ++ns) {
      int n = nb + ns * 16 + m;
      float bs = bsc[n];
#pragma unroll
      for (int ms = 0; ms < 4; ++ms) {
        unsigned short s4[4];
#pragma unroll
        for (int r = 0; r < 4; ++r) s4[r] = f2bf(accS[ms][ns][r] + bs);
        *(ushort4*)&ytr[n * 72 + ms * 16 + quad * 4] = *(const ushort4*)s4;
      }
    }
  }
  __syncthreads();
  {
    int n = t >> 1, half = t & 1;
    const unsigned short* lrow = ytr + n * 72 + half * 32;
    unsigned short* grow = scnchw + ((size_t)(b * 256 + n) << 12) + h * 64 + half * 32;
#pragma unroll
    for (int i = 0; i < 4; ++i)
      __builtin_nontemporal_store(*(const bf16x8*)(lrow + i * 8), (bf16x8*)(grow + i * 8));
  }
}

// ---------------- final: pure elementwise — ReLU(A*y + B + sc), NCHW streaming ----------------
// 2048 blocks x 256 thr: one (b, n) plane per block; 16 px/thread, fully coalesced.
__global__ __launch_bounds__(256) void k_final(const unsigned short* __restrict__ ynchw,
                                               const unsigned short* __restrict__ scnchw,
                                               const float* __restrict__ statsRaw,
                                               const float* __restrict__ gamma,
                                               const float* __restrict__ beta,
                                               float* __restrict__ out) {
  int blk = blockIdx.x;               // 2048; b = blk&7 (XCD-local), n = blk>>3
  int b = blk & 7, n = blk >> 3;
  int t = threadIdx.x;
  // stats finalize for channel n (redundant per thread; 16KB buffer is L2-hot)
  float s = 0.f, q = 0.f;
#pragma unroll
  for (int i = 0; i < 8; ++i) {
    float2 pq = *(const float2*)&statsRaw[((size_t)i * 256 + n) * 2];
    s += pq.x;
    q += pq.y;
  }
  float mean = s * (1.f / 32768.f);
  float var = q * (1.f / 32768.f) - mean * mean;
  float A = gamma[n] * rsqrtf(var + 1e-5f);
  float Bc = beta[n] - mean * A;
  size_t base = ((size_t)(b * 256 + n) << 12) + t * 16;
  const unsigned short* yp = ynchw + base;
  const unsigned short* sp = scnchw + base;
  float* op = out + base;
#pragma unroll
  for (int g = 0; g < 2; ++g) {
    bf16x8 yv = *(const bf16x8*)(yp + g * 8);
    bf16x8 sv = *(const bf16x8*)(sp + g * 8);
    f32x4 o0, o1;
#pragma unroll
    for (int j = 0; j < 4; ++j) {
      o0[j] = fmaxf(fmaf(bf2f((unsigned short)yv[j]), A, Bc) + bf2f((unsigned short)sv[j]), 0.f);
      o1[j] = fmaxf(fmaf(bf2f((unsigned short)yv[4 + j]), A, Bc) + bf2f((unsigned short)sv[4 + j]), 0.f);
    }
    *(f32x4*)(op + g * 8 + 0) = o0;
    *(f32x4*)(op + g * 8 + 4) = o1;
  }
}

extern "C" void kernel_launch(void* const* d_in, const int* in_sizes, int n_in,
                              void* d_out, int out_size, void* d_ws, size_t ws_size,
                              hipStream_t stream) {
  const float* x     = (const float*)d_in[0];
  const float* w_off = (const float*)d_in[1];
  const float* b_off = (const float*)d_in[2];
  const float* w_def = (const float*)d_in[3];
  const float* b_def = (const float*)d_in[4];
  const float* gamma = (const float*)d_in[5];
  const float* beta  = (const float*)d_in[6];
  const float* w_sc  = (const float*)d_in[7];
  const float* b_sc  = (const float*)d_in[8];
  float* out = (float*)d_out;

  char* ws = (char*)d_ws;
  unsigned short* xpad  = (unsigned short*)(ws + OFF_XPAD);
  unsigned short* wB    = (unsigned short*)(ws + OFF_WB);
  unsigned short* wS    = (unsigned short*)(ws + OFF_WS2);
  unsigned short* wO    = (unsigned short*)(ws + OFF_WO);
  unsigned short* ynchw = (unsigned short*)(ws + OFF_YM);
  unsigned short* scnch = (unsigned short*)(ws + OFF_SC);
  float* statsRaw       = (float*)(ws + OFF_SR);

  k_prep<<<691, 256, 0, stream>>>(x, xpad, w_def, w_sc, w_off, wB, wS, wO, statsRaw);
  k_main<<<512, 512, 0, stream>>>(xpad, wB, wO, wS, b_off, b_def, b_sc, ynchw, scnch, statsRaw);
  k_final<<<2048, 256, 0, stream>>>(ynchw, scnch, statsRaw, gamma, beta, out);
}

// Round 13
// 205.770 us; speedup vs baseline: 1.0962x; 1.0962x over previous
//
#include <hip/hip_runtime.h>

typedef __attribute__((ext_vector_type(8))) short bf16x8;
typedef __attribute__((ext_vector_type(4))) float f32x4;

__device__ __forceinline__ float bf2f(unsigned short u) {
  return __uint_as_float(((unsigned int)u) << 16);
}
__device__ __forceinline__ unsigned short f2bf(float f) {
  unsigned int u = __float_as_uint(f);
  u += 0x7fffu + ((u >> 16) & 1u);
  return (unsigned short)(u >> 16);
}

// ---------------- workspace layout (bytes) ----------------
constexpr size_t OFF_XPAD = 0;
constexpr size_t SZ_XPAD  = (size_t)8 * 66 * 66 * 128 * 2;        // 8,921,088
constexpr size_t OFF_WB   = OFF_XPAD + SZ_XPAD;
constexpr size_t SZ_WB    = (size_t)9 * 16 * 256 * 8 * 2;         // 589,824
constexpr size_t OFF_WS2  = OFF_WB + SZ_WB;
constexpr size_t SZ_WS2   = (size_t)16 * 256 * 8 * 2;             // 65,536
constexpr size_t OFF_WO   = OFF_WS2 + SZ_WS2;
constexpr size_t SZ_WO    = (size_t)9 * 16 * 32 * 8 * 2;          // 73,728
// y and shortcut, bf16, FINAL NCHW layout: [8][256][64*64]
constexpr size_t OFF_YM   = OFF_WO + SZ_WO;
constexpr size_t SZ_YM    = (size_t)8 * 256 * 4096 * 2;           // 16,777,216
constexpr size_t OFF_SC   = OFF_YM + SZ_YM;
constexpr size_t SZ_SC    = SZ_YM;                                 // 16,777,216
constexpr size_t OFF_SR   = OFF_SC + SZ_SC;                        // statsRaw [8][256][2] f32
constexpr size_t SZ_SR    = (size_t)8 * 256 * 2 * 4;              // 16,384

// XCD swizzle: b = blk&7 -> batch b on XCD b (R2: FETCH 26->7.3MB). BN stats via
// per-batch atomics (R6). At stride 140 = bank-conflict fix (R11: 2.47M->106K).
// NT stores ONLY with FULL-LINE-PER-INSTRUCTION coverage (R8, R12: partial-line NT
// = 2.8x write amplification via RMW). NCHW emit uses 8-lanes-per-row pattern:
// one instruction = one complete 128B w-row. ytr aliases At (R12's separate 37KB
// buffer pushed LDS to 77KB and halved residency).

// ---------------- prep: x transpose (0..511) + weight pack (512..689) + stats zero (690) ----------------
__global__ __launch_bounds__(256) void k_prep(const float* __restrict__ x,
                                              unsigned short* __restrict__ xp,
                                              const float* __restrict__ wdef,
                                              const float* __restrict__ wsc,
                                              const float* __restrict__ woff,
                                              unsigned short* __restrict__ wB,
                                              unsigned short* __restrict__ wS,
                                              unsigned short* __restrict__ wO,
                                              float* __restrict__ statsRaw) {
  int t = threadIdx.x;
  if (blockIdx.x == 690) {            // zero BN accumulators (graph-replay safe)
    for (int i = t; i < 4096; i += 256) statsRaw[i] = 0.f;
    return;
  }
  if (blockIdx.x >= 512) {            // ---- weight packing: 8 contiguous elems/thread ----
    int base = ((blockIdx.x - 512) * 256 + t) * 8;
    unsigned short w8[8];
    if (base < 294912) {
      int n = (base >> 3) & 255, kb = (base >> 11) & 15, tap = base >> 15;
#pragma unroll
      for (int j = 0; j < 8; ++j)
        w8[j] = f2bf(wdef[((size_t)n * 128 + kb * 8 + j) * 9 + tap]);
      *(bf16x8*)(wB + base) = *(const bf16x8*)w8;
    } else if (base < 327680) {
      int i0 = base - 294912;
      int n = (i0 >> 3) & 255, kb = i0 >> 11;
#pragma unroll
      for (int j = 0; j < 8; ++j)
        w8[j] = f2bf(wsc[(size_t)n * 128 + kb * 8 + j]);
      *(bf16x8*)(wS + i0) = *(const bf16x8*)w8;
    } else {
      int i0 = base - 327680;
      int n = (i0 >> 3) & 31, kb = (i0 >> 8) & 15, tap = i0 >> 12;
#pragma unroll
      for (int j = 0; j < 8; ++j)
        w8[j] = f2bf(n < 18 ? woff[((size_t)n * 128 + kb * 8 + j) * 9 + tap] : 0.f);
      *(bf16x8*)(wO + i0) = *(const bf16x8*)w8;
    }
    return;
  }
  // ---- x: NCHW fp32 -> NHWC bf16 zero-padded (+ halo zeroing) ----
  int blk = blockIdx.x;               // 512; b = blk&7 (XCD-local), h = blk>>3
  int b = blk & 7, h = blk >> 3;
  __shared__ unsigned short xt[128 * 68];   // [c][w], stride 68
  {
    unsigned short* base = xp + (size_t)b * 66 * 66 * 128;
    ushort4 z4 = {0, 0, 0, 0};
    if (t < 64) {                     // side columns of padded row h+1
      int col = (t >> 5) ? 65 : 0;
      int i = t & 31;
      *(ushort4*)(base + ((size_t)(h + 1) * 66 + col) * 128 + i * 4) = z4;
    }
    if (h == 0) {                     // top and bottom padded rows
      for (int i = t; i < 2112; i += 256) {
        *(ushort4*)(base + (size_t)i * 4) = z4;
        *(ushort4*)(base + (size_t)65 * 66 * 128 + (size_t)i * 4) = z4;
      }
    }
  }
  {
    // lane-coalesced load: consecutive lanes -> consecutive float4
#pragma unroll
    for (int i4 = 0; i4 < 8; ++i4) {
      int idx = t + i4 * 256;         // 0..2047 over 128 rows x 16 float4
      int row = idx >> 4, col = (idx & 15) * 4;
      float4 f = *(const float4*)&x[(((size_t)b * 128 + row) * 64 + h) * 64 + col];
      ushort4 u4;
      u4.x = f2bf(f.x); u4.y = f2bf(f.y); u4.z = f2bf(f.z); u4.w = f2bf(f.w);
      *(ushort4*)&xt[row * 68 + col] = u4;
    }
  }
  __syncthreads();
  {
    // column gather: lane = w (2-way bank alias only), cg = channel group
    int w = t & 63, cg = t >> 6;
    unsigned short tmp[32];
#pragma unroll
    for (int i = 0; i < 32; ++i) tmp[i] = xt[(cg * 32 + i) * 68 + w];
    unsigned short* dst = xp + ((size_t)(b * 66 + h + 1) * 66 + (w + 1)) * 128 + cg * 32;
#pragma unroll
    for (int i8 = 0; i8 < 4; ++i8)
      *(bf16x8*)(dst + i8 * 8) = *(const bf16x8*)&tmp[i8 * 8];
  }
}

// ---------------- main: offset conv + deform-sample + 3x3 GEMM + shortcut 1x1 + NCHW emit ----------------
// 512 blocks x 512 thr (8 waves). R10-verified tap loop (Breg preload) + stride-140
// At (bank fix). Epilogue: BN atomics, shortcut MFMA (xpad L2-hot), NCHW emit of y
// and sc via LDS transpose (ytr aliases At) + full-line NT stores.
__global__ __launch_bounds__(512, 4) void k_main(const unsigned short* __restrict__ xp,
                                                 const unsigned short* __restrict__ wB,
                                                 const unsigned short* __restrict__ wO,
                                                 const unsigned short* __restrict__ wS,
                                                 const float* __restrict__ boff,
                                                 const float* __restrict__ bdef,
                                                 const float* __restrict__ bsc,
                                                 unsigned short* __restrict__ ynchw,
                                                 unsigned short* __restrict__ scnchw,
                                                 float* __restrict__ statsRaw) {
  int blk = blockIdx.x;               // 512; b = blk&7 (XCD-local), h = blk>>3
  int b = blk & 7, h = blk >> 3;
  int t = threadIdx.x;
  int lane = t & 63, wid = t >> 6;    // 8 waves
  int m = lane & 15, quad = lane >> 4;
  __shared__ __align__(16) unsigned short At[2][64 * 140];  // 2 x 17920 B (stride 140)
  __shared__ float offsL[9][64][2];                          // 4608 B

  // ---- phase 0: inline offset conv (waves 0-3 compute this row's 18 offsets -> LDS) ----
  if (wid < 4) {
    f32x4 a0 = {0.f, 0.f, 0.f, 0.f}, a1 = {0.f, 0.f, 0.f, 0.f};
    int px = wid * 16 + m;
    const unsigned short* xbase = xp + ((size_t)(b * 66 + h) * 66 + px) * 128 + quad * 8;
    for (int tap = 0; tap < 9; ++tap) {
      const unsigned short* arow = xbase + ((tap / 3) * 66 + (tap % 3)) * 128;
#pragma unroll
      for (int kk = 0; kk < 4; ++kk) {
        bf16x8 a = *(const bf16x8*)(arow + kk * 32);
        const unsigned short* bb = wO + (size_t)(tap * 16 + kk * 4 + quad) * 256;
        bf16x8 b0 = *(const bf16x8*)(bb + m * 8);
        bf16x8 b1 = *(const bf16x8*)(bb + (16 + m) * 8);
        a0 = __builtin_amdgcn_mfma_f32_16x16x32_bf16(a, b0, a0, 0, 0, 0);
        a1 = __builtin_amdgcn_mfma_f32_16x16x32_bf16(a, b1, a1, 0, 0, 0);
      }
    }
#pragma unroll
    for (int r = 0; r < 4; ++r) {
      int pxs = wid * 16 + quad * 4 + r;
      offsL[m >> 1][pxs][m & 1] = a0[r] + boff[m];   // n=m in [0,16): tap=n>>1, comp=n&1
      if (m < 2) offsL[8][pxs][m] = a1[r] + boff[16 + m];
    }
  }

  f32x4 acc[4][2];
#pragma unroll
  for (int i = 0; i < 4; ++i)
#pragma unroll
    for (int j = 0; j < 2; ++j) acc[i][j] = (f32x4){0.f, 0.f, 0.f, 0.f};

  // sampling role: thread = px_s*8 + sub; 8 consecutive lanes cover one 128B chunk
  int px_s = t >> 3, sub = t & 7;
  const unsigned short* xb_base = xp + (size_t)b * 66 * 66 * 128;
  int nb = wid * 32;                  // mfma role: 32-ch N slice per wave, M=64 shared

  bf16x8 Breg[4][2];                  // this tap's wB fragments, preloaded
  auto loadB = [&](int tap) {
#pragma unroll
    for (int kk = 0; kk < 4; ++kk)
#pragma unroll
      for (int ns = 0; ns < 2; ++ns)
        Breg[kk][ns] = *(const bf16x8*)(wB + ((size_t)(tap * 16 + kk * 4 + quad) * 256 + nb + ns * 16 + m) * 8);
  };

  auto sample_prep = [&](int tap, float* wgt, const unsigned short** p) {
    float2 ov = *(const float2*)&offsL[tap][px_s][0];
    int ky = tap / 3 - 1, kx = tap % 3 - 1;
    float py = (float)(h + ky) + ov.x;
    float pxf = (float)(px_s + kx) + ov.y;
    float y0f = floorf(py), x0f = floorf(pxf);
    float fy = py - y0f, fx = pxf - x0f;
    int iy0 = (int)y0f, ix0 = (int)x0f;
#pragma unroll
    for (int j = 0; j < 4; ++j) {
      int iy = iy0 + (j >> 1), ix = ix0 + (j & 1);
      float wy = (j >> 1) ? fy : 1.f - fy;
      float wx = (j & 1) ? fx : 1.f - fx;
      bool valid = (iy >= 0) && (iy < 64) && (ix >= 0) && (ix < 64);
      int iyc = min(max(iy, 0), 63), ixc = min(max(ix, 0), 63);
      wgt[j] = valid ? wy * wx : 0.f;
      p[j] = xb_base + ((size_t)(iyc + 1) * 66 + (ixc + 1)) * 128 + sub * 8;
    }
  };
  auto load_g1 = [&](const unsigned short** p, int g, bf16x8* v) {
#pragma unroll
    for (int j = 0; j < 4; ++j)
      v[j] = *(const bf16x8*)(p[j] + g * 64);
  };
  auto store_g1 = [&](unsigned short* dst, int g, const float* wgt, bf16x8* v) {
    bf16x8 o;
#pragma unroll
    for (int j = 0; j < 8; ++j) {
      float s = fmaf(wgt[0], bf2f((unsigned short)v[0][j]),
                fmaf(wgt[1], bf2f((unsigned short)v[1][j]),
                fmaf(wgt[2], bf2f((unsigned short)v[2][j]),
                     wgt[3] * bf2f((unsigned short)v[3][j]))));
      o[j] = (short)f2bf(s);
    }
    *(bf16x8*)(dst + g * 64) = o;
  };
  auto mfma_half = [&](const unsigned short* buf, int kk0) {
#pragma unroll
    for (int kk = kk0; kk < kk0 + 2; ++kk) {
      bf16x8 af[4];
#pragma unroll
      for (int ms = 0; ms < 4; ++ms)
        af[ms] = *(const bf16x8*)(buf + (ms * 16 + m) * 140 + kk * 32 + quad * 8);
#pragma unroll
      for (int ns = 0; ns < 2; ++ns)
#pragma unroll
        for (int ms = 0; ms < 4; ++ms)
          acc[ms][ns] = __builtin_amdgcn_mfma_f32_16x16x32_bf16(af[ms], Breg[kk][ns], acc[ms][ns], 0, 0, 0);
    }
  };

  // prologue: B-frags for tap 0, then sample tap 0 into buf 0
  loadB(0);
  __syncthreads();                    // offsL ready
  {
    float wgt[4]; const unsigned short* p[4]; bf16x8 v0[4], v1[4];
    sample_prep(0, wgt, p);
    unsigned short* dst = &At[0][px_s * 140 + sub * 8];
    load_g1(p, 0, v0); load_g1(p, 1, v1);
    store_g1(dst, 0, wgt, v0); store_g1(dst, 1, wgt, v1);
  }
#pragma unroll
  for (int tap = 0; tap < 9; ++tap) {
    __syncthreads();
    const unsigned short* cur = At[tap & 1];
    unsigned short* dst = &At[(tap + 1) & 1][px_s * 140 + sub * 8];
    if (tap < 8) {
      float wgt[4]; const unsigned short* p[4]; bf16x8 v0[4], v1[4];
      sample_prep(tap + 1, wgt, p);
      load_g1(p, 0, v0);
      load_g1(p, 1, v1);
      mfma_half(cur, 0);              // regs + ds_read only: no vmcnt dependence
      store_g1(dst, 0, wgt, v0);
      mfma_half(cur, 2);
      loadB(tap + 1);                 // prefetch next tap's B
      store_g1(dst, 1, wgt, v1);
    } else {
      mfma_half(cur, 0);
      mfma_half(cur, 2);
    }
  }

  // ---- epilogue 1: bias fold + BN atomics ----
#pragma unroll
  for (int ns = 0; ns < 2; ++ns) {
    int n = nb + ns * 16 + m;
    float bias = bdef[n];
    float s = 0.f, q = 0.f;
#pragma unroll
    for (int ms = 0; ms < 4; ++ms)
#pragma unroll
      for (int r = 0; r < 4; ++r) {
        float v = acc[ms][ns][r] + bias;
        acc[ms][ns][r] = v;
        s += v;
        q += v * v;
      }
    s += __shfl_xor(s, 16); s += __shfl_xor(s, 32);
    q += __shfl_xor(q, 16); q += __shfl_xor(q, 32);
    if (quad == 0) {                  // 64 blocks share each address (batch-local)
      atomicAdd(&statsRaw[((size_t)b * 256 + n) * 2 + 0], s);
      atomicAdd(&statsRaw[((size_t)b * 256 + n) * 2 + 1], q);
    }
  }

  // ---- epilogue 2: 1x1 shortcut MFMA (xpad center row is L2-hot) ----
  f32x4 accS[4][2];
#pragma unroll
  for (int i = 0; i < 4; ++i)
#pragma unroll
    for (int j = 0; j < 2; ++j) accS[i][j] = (f32x4){0.f, 0.f, 0.f, 0.f};
  {
    const unsigned short* xrow = xp + ((size_t)(b * 66 + h + 1) * 66 + 1) * 128;
#pragma unroll
    for (int kk = 0; kk < 4; ++kk) {
      bf16x8 af[4];
#pragma unroll
      for (int ms = 0; ms < 4; ++ms)
        af[ms] = *(const bf16x8*)(xrow + (ms * 16 + m) * 128 + kk * 32 + quad * 8);
#pragma unroll
      for (int ns = 0; ns < 2; ++ns) {
        bf16x8 bfr = *(const bf16x8*)(wS + ((size_t)(kk * 4 + quad) * 256 + nb + ns * 16 + m) * 8);
#pragma unroll
        for (int ms = 0; ms < 4; ++ms)
          accS[ms][ns] = __builtin_amdgcn_mfma_f32_16x16x32_bf16(af[ms], bfr, accS[ms][ns], 0, 0, 0);
      }
    }
  }

  // ---- epilogue 3: NCHW emit of y then sc; ytr aliases At; full-line NT stores ----
  __syncthreads();                    // all waves done reading At
  unsigned short* ytr = &At[0][0];    // 256 rows x stride 68 = 34,816 B (fits in At)
  {
#pragma unroll
    for (int ns = 0; ns < 2; ++ns) {
      int n = nb + ns * 16 + m;
#pragma unroll
      for (int ms = 0; ms < 4; ++ms) {
        unsigned short y4[4];
#pragma unroll
        for (int r = 0; r < 4; ++r) y4[r] = f2bf(acc[ms][ns][r]);
        *(ushort4*)&ytr[n * 68 + ms * 16 + quad * 4] = *(const ushort4*)y4;
      }
    }
  }
  __syncthreads();
  {
    // 8 lanes per channel-row: one NT instruction = one complete 128B w-row
    int nrow = t >> 3, sub8 = t & 7;  // 64 rows/pass, 4 passes
#pragma unroll
    for (int p = 0; p < 4; ++p) {
      int n = p * 64 + nrow;
      __builtin_nontemporal_store(*(const bf16x8*)&ytr[n * 68 + sub8 * 8],
          (bf16x8*)(ynchw + ((size_t)(b * 256 + n) << 12) + h * 64 + sub8 * 8));
    }
  }
  __syncthreads();
  {
#pragma unroll
    for (int ns = 0; ns < 2; ++ns) {
      int n = nb + ns * 16 + m;
      float bs = bsc[n];
#pragma unroll
      for (int ms = 0; ms < 4; ++ms) {
        unsigned short s4[4];
#pragma unroll
        for (int r = 0; r < 4; ++r) s4[r] = f2bf(accS[ms][ns][r] + bs);
        *(ushort4*)&ytr[n * 68 + ms * 16 + quad * 4] = *(const ushort4*)s4;
      }
    }
  }
  __syncthreads();
  {
    int nrow = t >> 3, sub8 = t & 7;
#pragma unroll
    for (int p = 0; p < 4; ++p) {
      int n = p * 64 + nrow;
      __builtin_nontemporal_store(*(const bf16x8*)&ytr[n * 68 + sub8 * 8],
          (bf16x8*)(scnchw + ((size_t)(b * 256 + n) << 12) + h * 64 + sub8 * 8));
    }
  }
}

// ---------------- final: pure elementwise — ReLU(A*y + B + sc), NCHW streaming ----------------
// 2048 blocks x 256 thr: one (b, n) plane per block; 16 px/thread, fully coalesced.
__global__ __launch_bounds__(256) void k_final(const unsigned short* __restrict__ ynchw,
                                               const unsigned short* __restrict__ scnchw,
                                               const float* __restrict__ statsRaw,
                                               const float* __restrict__ gamma,
                                               const float* __restrict__ beta,
                                               float* __restrict__ out) {
  int blk = blockIdx.x;               // 2048; b = blk&7 (XCD-local), n = blk>>3
  int b = blk & 7, n = blk >> 3;
  int t = threadIdx.x;
  // stats finalize for channel n (redundant per thread; 16KB buffer is L2-hot)
  float s = 0.f, q = 0.f;
#pragma unroll
  for (int i = 0; i < 8; ++i) {
    float2 pq = *(const float2*)&statsRaw[((size_t)i * 256 + n) * 2];
    s += pq.x;
    q += pq.y;
  }
  float mean = s * (1.f / 32768.f);
  float var = q * (1.f / 32768.f) - mean * mean;
  float A = gamma[n] * rsqrtf(var + 1e-5f);
  float Bc = beta[n] - mean * A;
  size_t base = ((size_t)(b * 256 + n) << 12) + t * 16;
  const unsigned short* yp = ynchw + base;
  const unsigned short* sp = scnchw + base;
  float* op = out + base;
#pragma unroll
  for (int g = 0; g < 2; ++g) {
    bf16x8 yv = *(const bf16x8*)(yp + g * 8);
    bf16x8 sv = *(const bf16x8*)(sp + g * 8);
    f32x4 o0, o1;
#pragma unroll
    for (int j = 0; j < 4; ++j) {
      o0[j] = fmaxf(fmaf(bf2f((unsigned short)yv[j]), A, Bc) + bf2f((unsigned short)sv[j]), 0.f);
      o1[j] = fmaxf(fmaf(bf2f((unsigned short)yv[4 + j]), A, Bc) + bf2f((unsigned short)sv[4 + j]), 0.f);
    }
    *(f32x4*)(op + g * 8 + 0) = o0;
    *(f32x4*)(op + g * 8 + 4) = o1;
  }
}

extern "C" void kernel_launch(void* const* d_in, const int* in_sizes, int n_in,
                              void* d_out, int out_size, void* d_ws, size_t ws_size,
                              hipStream_t stream) {
  const float* x     = (const float*)d_in[0];
  const float* w_off = (const float*)d_in[1];
  const float* b_off = (const float*)d_in[2];
  const float* w_def = (const float*)d_in[3];
  const float* b_def = (const float*)d_in[4];
  const float* gamma = (const float*)d_in[5];
  const float* beta  = (const float*)d_in[6];
  const float* w_sc  = (const float*)d_in[7];
  const float* b_sc  = (const float*)d_in[8];
  float* out = (float*)d_out;

  char* ws = (char*)d_ws;
  unsigned short* xpad  = (unsigned short*)(ws + OFF_XPAD);
  unsigned short* wB    = (unsigned short*)(ws + OFF_WB);
  unsigned short* wS    = (unsigned short*)(ws + OFF_WS2);
  unsigned short* wO    = (unsigned short*)(ws + OFF_WO);
  unsigned short* ynchw = (unsigned short*)(ws + OFF_YM);
  unsigned short* scnch = (unsigned short*)(ws + OFF_SC);
  float* statsRaw       = (float*)(ws + OFF_SR);

  k_prep<<<691, 256, 0, stream>>>(x, xpad, w_def, w_sc, w_off, wB, wS, wO, statsRaw);
  k_main<<<512, 512, 0, stream>>>(xpad, wB, wO, wS, b_off, b_def, b_sc, ynchw, scnch, statsRaw);
  k_final<<<2048, 256, 0, stream>>>(ynchw, scnch, statsRaw, gamma, beta, out);
}

// Round 15
// 195.144 us; speedup vs baseline: 1.1559x; 1.0545x over previous
//
#include <hip/hip_runtime.h>

typedef __attribute__((ext_vector_type(8))) short bf16x8;
typedef __attribute__((ext_vector_type(4))) float f32x4;

__device__ __forceinline__ float bf2f(unsigned short u) {
  return __uint_as_float(((unsigned int)u) << 16);
}
__device__ __forceinline__ unsigned short f2bf(float f) {
  unsigned int u = __float_as_uint(f);
  u += 0x7fffu + ((u >> 16) & 1u);
  return (unsigned short)(u >> 16);
}

// ---------------- workspace layout (bytes) ----------------
constexpr size_t OFF_XPAD = 0;
constexpr size_t SZ_XPAD  = (size_t)8 * 66 * 66 * 128 * 2;        // 8,921,088
constexpr size_t OFF_WB   = OFF_XPAD + SZ_XPAD;
constexpr size_t SZ_WB    = (size_t)9 * 16 * 256 * 8 * 2;         // 589,824
constexpr size_t OFF_WS2  = OFF_WB + SZ_WB;
constexpr size_t SZ_WS2   = (size_t)16 * 256 * 8 * 2;             // 65,536
constexpr size_t OFF_WO   = OFF_WS2 + SZ_WS2;
constexpr size_t SZ_WO    = (size_t)9 * 16 * 32 * 8 * 2;          // 73,728
// y_main bf16 [32768][256]
constexpr size_t OFF_YM   = OFF_WO + SZ_WO;
constexpr size_t SZ_YM    = (size_t)32768 * 256 * 2;              // 16,777,216
constexpr size_t OFF_SR   = OFF_YM + SZ_YM;                        // statsRaw [8][256][2] f32
constexpr size_t SZ_SR    = (size_t)8 * 256 * 2 * 4;              // 16,384

// R14 = exact R6 structure (best verified: 149.5us) + At stride 136->140.
// XCD swizzle: b = blk&7 -> batch b on XCD b (R2: FETCH 26.4->7.3MB).
// BN stats via per-batch atomics into statsRaw, zeroed by k_prep (R6).
// At stride 140 shorts: 280B = 6 dwords mod 32 -> ds_write_b128 ~2-way (free);
// old 136 (272B = 4 mod 32) was 8-way (R11/R13: conflicts 2.47M -> 106K).
// R8-R13 architecture experiments (fragment-linear ymain, NCHW emit in k_main,
// pure-stream k_final) all lost to this shape: the (b,h)->(b,n) layout scatter
// is cheapest absorbed by R6's k_final, and NT-vs-plain ymain is zero-sum.

// ---------------- fused prep: x transpose (0..511) + weight pack (512..1935) + stats zero (1936) ----------------
__global__ __launch_bounds__(256) void k_prep(const float* __restrict__ x,
                                              unsigned short* __restrict__ xp,
                                              const float* __restrict__ wdef,
                                              const float* __restrict__ wsc,
                                              const float* __restrict__ woff,
                                              unsigned short* __restrict__ wB,
                                              unsigned short* __restrict__ wS,
                                              unsigned short* __restrict__ wO,
                                              float* __restrict__ statsRaw) {
  int t = threadIdx.x;
  if (blockIdx.x == 1936) {           // zero BN accumulators (graph-replay safe)
    for (int i = t; i < 4096; i += 256) statsRaw[i] = 0.f;
    return;
  }
  if (blockIdx.x >= 512) {            // ---- weight packing part ----
    int tid = (blockIdx.x - 512) * 256 + t;
    if (tid < 294912) {
      int k8 = tid & 7, n = (tid >> 3) & 255, kb = (tid >> 11) & 15, tap = tid >> 15;
      int c = kb * 8 + k8;
      wB[tid] = f2bf(wdef[((size_t)n * 128 + c) * 9 + tap]);
    } else if (tid < 294912 + 32768) {
      int i = tid - 294912;
      int k8 = i & 7, n = (i >> 3) & 255, kb = i >> 11;
      wS[i] = f2bf(wsc[(size_t)n * 128 + kb * 8 + k8]);
    } else if (tid < 294912 + 32768 + 36864) {
      int i = tid - 327680;
      int k8 = i & 7, n = (i >> 3) & 31, kb = (i >> 8) & 15, tap = i >> 12;
      int c = kb * 8 + k8;
      wO[i] = f2bf(n < 18 ? woff[((size_t)n * 128 + c) * 9 + tap] : 0.f);
    }
    return;
  }
  // ---- x: NCHW fp32 -> NHWC bf16 zero-padded (+ halo zeroing, no memset) ----
  int blk = blockIdx.x;               // 512; b = blk&7 (XCD-local), h = blk>>3
  int b = blk & 7, h = blk >> 3;
  __shared__ unsigned short xt[128 * 68];   // [c][w], stride 68
  {
    unsigned short* base = xp + (size_t)b * 66 * 66 * 128;
    ushort4 z4 = {0, 0, 0, 0};
    if (t < 64) {                     // side columns of padded row h+1
      int col = (t >> 5) ? 65 : 0;
      int i = t & 31;
      *(ushort4*)(base + ((size_t)(h + 1) * 66 + col) * 128 + i * 4) = z4;
    }
    if (h == 0) {                     // top and bottom padded rows
      for (int i = t; i < 2112; i += 256) {
        *(ushort4*)(base + (size_t)i * 4) = z4;
        *(ushort4*)(base + (size_t)65 * 66 * 128 + (size_t)i * 4) = z4;
      }
    }
  }
  {
    int c = t >> 1, w0 = (t & 1) * 32;
    const float4* xs = (const float4*)&x[(((size_t)b * 128 + c) * 64 + h) * 64 + w0];
    unsigned short* row = &xt[c * 68 + w0];
#pragma unroll
    for (int i4 = 0; i4 < 8; ++i4) {
      float4 f = xs[i4];
      ushort4 u4;
      u4.x = f2bf(f.x); u4.y = f2bf(f.y); u4.z = f2bf(f.z); u4.w = f2bf(f.w);
      *(ushort4*)(row + i4 * 4) = u4;
    }
  }
  __syncthreads();
  {
    int w = t >> 2, c0 = (t & 3) * 32;
    unsigned short tmp[32];
#pragma unroll
    for (int i = 0; i < 32; ++i) tmp[i] = xt[(c0 + i) * 68 + w];
    unsigned short* dst = xp + ((size_t)(b * 66 + h + 1) * 66 + (w + 1)) * 128 + c0;
#pragma unroll
    for (int i8 = 0; i8 < 4; ++i8)
      *(bf16x8*)(dst + i8 * 8) = *(const bf16x8*)&tmp[i8 * 8];
  }
}

// ---------------- main: offset conv + deform-sample + 3x3 conv GEMM + BN atomics ----------------
// 512 blocks x 512 thr (8 waves); Breg preload keeps MFMA off the vmcnt FIFO chain.
__global__ __launch_bounds__(512, 4) void k_main(const unsigned short* __restrict__ xp,
                                                 const unsigned short* __restrict__ wB,
                                                 const unsigned short* __restrict__ wO,
                                                 const float* __restrict__ boff,
                                                 const float* __restrict__ bdef,
                                                 unsigned short* __restrict__ ymain,
                                                 float* __restrict__ statsRaw) {
  int blk = blockIdx.x;               // 512; b = blk&7 (XCD-local), h = blk>>3
  int b = blk & 7, h = blk >> 3;
  int bh = (b << 6) + h;              // linear row id for ymain layout
  int t = threadIdx.x;
  int lane = t & 63, wid = t >> 6;    // 8 waves
  int m = lane & 15, quad = lane >> 4;
  __shared__ __align__(16) unsigned short At[2][64 * 140];  // 2 x 17920 B (stride 140)
  __shared__ float offsL[9][64][2];                          // 4608 B

  // ---- phase 0: inline offset conv (waves 0-3 compute this row's 18 offsets -> LDS) ----
  if (wid < 4) {
    f32x4 a0 = {0.f, 0.f, 0.f, 0.f}, a1 = {0.f, 0.f, 0.f, 0.f};
    int px = wid * 16 + m;
    const unsigned short* xbase = xp + ((size_t)(b * 66 + h) * 66 + px) * 128 + quad * 8;
    for (int tap = 0; tap < 9; ++tap) {
      const unsigned short* arow = xbase + ((tap / 3) * 66 + (tap % 3)) * 128;
#pragma unroll
      for (int kk = 0; kk < 4; ++kk) {
        bf16x8 a = *(const bf16x8*)(arow + kk * 32);
        const unsigned short* bb = wO + (size_t)(tap * 16 + kk * 4 + quad) * 256;
        bf16x8 b0 = *(const bf16x8*)(bb + m * 8);
        bf16x8 b1 = *(const bf16x8*)(bb + (16 + m) * 8);
        a0 = __builtin_amdgcn_mfma_f32_16x16x32_bf16(a, b0, a0, 0, 0, 0);
        a1 = __builtin_amdgcn_mfma_f32_16x16x32_bf16(a, b1, a1, 0, 0, 0);
      }
    }
#pragma unroll
    for (int r = 0; r < 4; ++r) {
      int pxs = wid * 16 + quad * 4 + r;
      offsL[m >> 1][pxs][m & 1] = a0[r] + boff[m];   // n=m in [0,16): tap=n>>1, comp=n&1
      if (m < 2) offsL[8][pxs][m] = a1[r] + boff[16 + m];
    }
  }

  f32x4 acc[4][2];
#pragma unroll
  for (int i = 0; i < 4; ++i)
#pragma unroll
    for (int j = 0; j < 2; ++j) acc[i][j] = (f32x4){0.f, 0.f, 0.f, 0.f};

  // sampling role: thread = px_s*8 + sub; 8 consecutive lanes cover one 128B chunk
  int px_s = t >> 3, sub = t & 7;
  const unsigned short* xb_base = xp + (size_t)b * 66 * 66 * 128;
  int nb = wid * 32;                  // mfma role: 32-ch N slice per wave, M=64 shared

  bf16x8 Breg[4][2];                  // this tap's wB fragments, preloaded
  auto loadB = [&](int tap) {
#pragma unroll
    for (int kk = 0; kk < 4; ++kk)
#pragma unroll
      for (int ns = 0; ns < 2; ++ns)
        Breg[kk][ns] = *(const bf16x8*)(wB + ((size_t)(tap * 16 + kk * 4 + quad) * 256 + nb + ns * 16 + m) * 8);
  };

  auto sample_prep = [&](int tap, float* wgt, const unsigned short** p) {
    float2 ov = *(const float2*)&offsL[tap][px_s][0];
    int ky = tap / 3 - 1, kx = tap % 3 - 1;
    float py = (float)(h + ky) + ov.x;
    float pxf = (float)(px_s + kx) + ov.y;
    float y0f = floorf(py), x0f = floorf(pxf);
    float fy = py - y0f, fx = pxf - x0f;
    int iy0 = (int)y0f, ix0 = (int)x0f;
#pragma unroll
    for (int j = 0; j < 4; ++j) {
      int iy = iy0 + (j >> 1), ix = ix0 + (j & 1);
      float wy = (j >> 1) ? fy : 1.f - fy;
      float wx = (j & 1) ? fx : 1.f - fx;
      bool valid = (iy >= 0) && (iy < 64) && (ix >= 0) && (ix < 64);
      int iyc = min(max(iy, 0), 63), ixc = min(max(ix, 0), 63);
      wgt[j] = valid ? wy * wx : 0.f;
      p[j] = xb_base + ((size_t)(iyc + 1) * 66 + (ixc + 1)) * 128 + sub * 8;
    }
  };
  auto load_g1 = [&](const unsigned short** p, int g, bf16x8* v) {
#pragma unroll
    for (int j = 0; j < 4; ++j)
      v[j] = *(const bf16x8*)(p[j] + g * 64);
  };
  auto store_g1 = [&](unsigned short* dst, int g, const float* wgt, bf16x8* v) {
    bf16x8 o;
#pragma unroll
    for (int j = 0; j < 8; ++j) {
      float s = fmaf(wgt[0], bf2f((unsigned short)v[0][j]),
                fmaf(wgt[1], bf2f((unsigned short)v[1][j]),
                fmaf(wgt[2], bf2f((unsigned short)v[2][j]),
                     wgt[3] * bf2f((unsigned short)v[3][j]))));
      o[j] = (short)f2bf(s);
    }
    *(bf16x8*)(dst + g * 64) = o;
  };
  auto mfma_half = [&](const unsigned short* buf, int kk0) {
#pragma unroll
    for (int kk = kk0; kk < kk0 + 2; ++kk) {
      bf16x8 af[4];
#pragma unroll
      for (int ms = 0; ms < 4; ++ms)
        af[ms] = *(const bf16x8*)(buf + (ms * 16 + m) * 140 + kk * 32 + quad * 8);
#pragma unroll
      for (int ns = 0; ns < 2; ++ns)
#pragma unroll
        for (int ms = 0; ms < 4; ++ms)
          acc[ms][ns] = __builtin_amdgcn_mfma_f32_16x16x32_bf16(af[ms], Breg[kk][ns], acc[ms][ns], 0, 0, 0);
    }
  };

  // prologue: B-frags for tap 0, then sample tap 0 into buf 0
  loadB(0);
  __syncthreads();                    // offsL ready
  {
    float wgt[4]; const unsigned short* p[4]; bf16x8 v0[4], v1[4];
    sample_prep(0, wgt, p);
    unsigned short* dst = &At[0][px_s * 140 + sub * 8];
    load_g1(p, 0, v0); load_g1(p, 1, v1);
    store_g1(dst, 0, wgt, v0); store_g1(dst, 1, wgt, v1);
  }
#pragma unroll
  for (int tap = 0; tap < 9; ++tap) {
    __syncthreads();
    const unsigned short* cur = At[tap & 1];
    unsigned short* dst = &At[(tap + 1) & 1][px_s * 140 + sub * 8];
    if (tap < 8) {
      float wgt[4]; const unsigned short* p[4]; bf16x8 v0[4], v1[4];
      sample_prep(tap + 1, wgt, p);
      load_g1(p, 0, v0);
      load_g1(p, 1, v1);
      mfma_half(cur, 0);              // regs + ds_read only: no vmcnt dependence
      store_g1(dst, 0, wgt, v0);
      mfma_half(cur, 2);
      loadB(tap + 1);                 // prefetch next tap's B
      store_g1(dst, 1, wgt, v1);
    } else {
      mfma_half(cur, 0);
      mfma_half(cur, 2);
    }
  }

  // ---- epilogue: bias + BN atomics; LDS transpose -> coalesced bf16 stores ----
  __syncthreads();                    // all waves done reading At
  unsigned short* yb = &At[0][0];     // 64 x 264 bf16 (33,792 B <= 35,840 B)
#pragma unroll
  for (int ns = 0; ns < 2; ++ns) {
    int n = nb + ns * 16 + m;
    float bias = bdef[n];
    float s = 0.f, q = 0.f;
#pragma unroll
    for (int ms = 0; ms < 4; ++ms) {
#pragma unroll
      for (int r = 0; r < 4; ++r) {
        int px = ms * 16 + quad * 4 + r;
        float v = acc[ms][ns][r] + bias;
        yb[px * 264 + n] = f2bf(v);
        s += v;
        q += v * v;
      }
    }
    s += __shfl_xor(s, 16); s += __shfl_xor(s, 32);
    q += __shfl_xor(q, 16); q += __shfl_xor(q, 32);
    if (quad == 0) {                  // 64 blocks share each address (batch-local)
      atomicAdd(&statsRaw[((size_t)b * 256 + n) * 2 + 0], s);
      atomicAdd(&statsRaw[((size_t)b * 256 + n) * 2 + 1], q);
    }
  }
  __syncthreads();
  {
    unsigned short* grow = ymain + (size_t)(bh * 64 + px_s) * 256;
    const unsigned short* lrow = yb + px_s * 264;
#pragma unroll
    for (int k = 0; k < 4; ++k) {
      int n0 = k * 64 + sub * 8;      // 8 consecutive lanes -> one 128B chunk
      __builtin_nontemporal_store(*(const bf16x8*)(lrow + n0), (bf16x8*)(grow + n0));
    }
  }
}

// ---------------- final: stats finalize + 1x1 shortcut MFMA + BN apply + ReLU + NCHW store ----------------
// 1024 blocks x 32-px tiles; batch->XCD swizzle; per-block stats finalize from 16KB statsRaw.
__global__ __launch_bounds__(256) void k_final(const unsigned short* __restrict__ xp,
                                               const unsigned short* __restrict__ wS,
                                               const unsigned short* __restrict__ ymain,
                                               const float* __restrict__ statsRaw,
                                               const float* __restrict__ gamma,
                                               const float* __restrict__ beta,
                                               const float* __restrict__ bsc,
                                               float* __restrict__ out) {
  int blk = blockIdx.x;               // 1024; b = blk&7 (XCD-local)
  int b = blk & 7, rem = blk >> 3, h = rem >> 1, half = rem & 1;
  int px0 = half * 32;
  int bh = (b << 6) + h;
  int t = threadIdx.x;
  int lane = t & 63, wid = t >> 6;
  int m = lane & 15, quad = lane >> 4;
  __shared__ float tr[128 * 35];      // 17,920 B
  __shared__ float sAB[512];          // [0:256) scale, [256:512) shift
  // phase 0: stats finalize (cheap: 8 adds/channel from 16KB buffer)
  {
    float s = 0.f, q = 0.f;
#pragma unroll
    for (int i = 0; i < 8; ++i) {
      float2 pq = *(const float2*)&statsRaw[((size_t)i * 256 + t) * 2];
      s += pq.x;
      q += pq.y;
    }
    float mean = s * (1.f / 32768.f);
    float var = q * (1.f / 32768.f) - mean * mean;
    float inv = rsqrtf(var + 1e-5f);
    float A = gamma[t] * inv;
    sAB[t] = A;
    sAB[256 + t] = beta[t] - mean * A;
  }
  f32x4 acc[2][4];
#pragma unroll
  for (int i = 0; i < 2; ++i)
#pragma unroll
    for (int j = 0; j < 4; ++j) acc[i][j] = (f32x4){0.f, 0.f, 0.f, 0.f};
  const unsigned short* xrow = xp + ((size_t)(b * 66 + h + 1) * 66 + 1 + px0) * 128;
  int nb = wid * 64;
#pragma unroll
  for (int kk = 0; kk < 4; ++kk) {
    bf16x8 af[2];
#pragma unroll
    for (int ms = 0; ms < 2; ++ms)
      af[ms] = *(const bf16x8*)(xrow + (ms * 16 + m) * 128 + kk * 32 + quad * 8);
#pragma unroll
    for (int ns = 0; ns < 4; ++ns) {
      bf16x8 bfr = *(const bf16x8*)(wS + ((size_t)(kk * 4 + quad) * 256 + nb + ns * 16 + m) * 8);
#pragma unroll
      for (int ms = 0; ms < 2; ++ms)
        acc[ms][ns] = __builtin_amdgcn_mfma_f32_16x16x32_bf16(af[ms], bfr, acc[ms][ns], 0, 0, 0);
    }
  }
  __syncthreads();                    // sAB ready (also covers tr reuse below)
  for (int pass = 0; pass < 2; ++pass) {
    if ((wid >> 1) == pass) {
#pragma unroll
      for (int ns = 0; ns < 4; ++ns) {
        int n = nb + ns * 16 + m;
        float bs = bsc[n];
        int nl = n - pass * 128;
#pragma unroll
        for (int ms = 0; ms < 2; ++ms)
#pragma unroll
          for (int r = 0; r < 4; ++r) {
            int px = ms * 16 + quad * 4 + r;
            tr[nl * 35 + px] = acc[ms][ns][r] + bs;
          }
      }
    }
    __syncthreads();
    {
      int nl2 = t & 63, g = t >> 6;
      int n = pass * 128 + nl2 * 2;
      float A0 = sAB[n], B0 = sAB[256 + n];
      float A1 = sAB[n + 1], B1 = sAB[256 + n + 1];
#pragma unroll
      for (int i = 0; i < 8; ++i) {
        int pxl = g * 8 + i;
        unsigned int ym2 = *(const unsigned int*)(ymain + (size_t)(bh * 64 + px0 + pxl) * 256 + n);
        float y0 = bf2f((unsigned short)(ym2 & 0xffffu));
        float y1 = bf2f((unsigned short)(ym2 >> 16));
        int nl = nl2 * 2;
        float* p0 = &tr[nl * 35 + pxl];
        float* p1 = &tr[(nl + 1) * 35 + pxl];
        *p0 = fmaxf(fmaf(y0, A0, B0) + *p0, 0.f);
        *p1 = fmaxf(fmaf(y1, A1, B1) + *p1, 0.f);
      }
    }
    __syncthreads();
    {
      int ww = t & 31, ng = t >> 5;
#pragma unroll
      for (int i = 0; i < 16; ++i) {
        int nl = ng * 16 + i;
        out[((size_t)(b * 256 + pass * 128 + nl) * 64 + h) * 64 + px0 + ww] = tr[nl * 35 + ww];
      }
    }
    __syncthreads();
  }
}

extern "C" void kernel_launch(void* const* d_in, const int* in_sizes, int n_in,
                              void* d_out, int out_size, void* d_ws, size_t ws_size,
                              hipStream_t stream) {
  const float* x     = (const float*)d_in[0];
  const float* w_off = (const float*)d_in[1];
  const float* b_off = (const float*)d_in[2];
  const float* w_def = (const float*)d_in[3];
  const float* b_def = (const float*)d_in[4];
  const float* gamma = (const float*)d_in[5];
  const float* beta  = (const float*)d_in[6];
  const float* w_sc  = (const float*)d_in[7];
  const float* b_sc  = (const float*)d_in[8];
  float* out = (float*)d_out;

  char* ws = (char*)d_ws;
  unsigned short* xpad  = (unsigned short*)(ws + OFF_XPAD);
  unsigned short* wB    = (unsigned short*)(ws + OFF_WB);
  unsigned short* wS    = (unsigned short*)(ws + OFF_WS2);
  unsigned short* wO    = (unsigned short*)(ws + OFF_WO);
  unsigned short* ymain = (unsigned short*)(ws + OFF_YM);
  float* statsRaw       = (float*)(ws + OFF_SR);

  k_prep<<<1937, 256, 0, stream>>>(x, xpad, w_def, w_sc, w_off, wB, wS, wO, statsRaw);
  k_main<<<512, 512, 0, stream>>>(xpad, wB, wO, b_off, b_def, ymain, statsRaw);
  k_final<<<1024, 256, 0, stream>>>(xpad, wS, ymain, statsRaw, gamma, beta, b_sc, out);
}